// Round 9
// baseline (1311.444 us; speedup 1.0000x reference)
//
#include <hip/hip_runtime.h>
#include <hip/hip_bf16.h>

// GCN forward: 2-layer GCNConv + log_softmax.
// N=100000, E=3200000, F_IN=2000, H=16, C=3.
//
// R8 post-mortem: gemm measured 559us solo; all utilization counters ~10-30%;
// per-chunk latency ~13-21k cy. Diagnosis: staging read x in 160B stripes at
// 8KB stride -> ~25% DRAM efficiency (0.8-1.9 TB/s plateau across R2/R6-R8,
// invariant to occupancy). R9 gemm: K-chunk=256 so each wave-instruction
// reads 1KB CONTIGUOUS (one row's chunk); LDS 64KB swizzled [k4][row];
// single-buffer LDS + register double-buffer; W1 via L1 broadcast.
//
//  K0  zero_k    : cnt+cursor = 0
//  K1  count_k   : cnt[dst]++ over edges (int4 x4 edges/thread)
//  K2  scan_k    : rowptr = exclusive_scan(cnt); dinv = rsqrt(cnt+1) fused
//  K3  scatter_k : CSR col array (int4 x4 edges/thread)
//  K4  gemm1     : t1s[row] = (x[row] @ W1) * dinv[row]
//  K5  agg1      : h = relu(dinv*(t1s[i]+sum t1s[col])+b1); t2s=(h@W2)*dinv
//  K6  agg2      : logits + log_softmax -> out

#define FIN   2000
#define HDIM  16
#define RPB   64          // rows per block
#define KC    256         // k per chunk (1KB per row-chunk -> contiguous reads)
#define NCH   8           // chunks: 7 full + tail of 208 (52 float4)

__global__ void zero_k(int4* __restrict__ p, int n4) {
    int i = blockIdx.x * 256 + threadIdx.x;
    if (i < n4) p[i] = make_int4(0, 0, 0, 0);
}

__global__ void count_k(const int* __restrict__ dst, int* __restrict__ cnt, int e) {
    int i = (blockIdx.x * 256 + threadIdx.x) * 4;
    if (i + 3 < e) {
        int4 d = *(const int4*)(dst + i);
        atomicAdd(&cnt[d.x], 1);
        atomicAdd(&cnt[d.y], 1);
        atomicAdd(&cnt[d.z], 1);
        atomicAdd(&cnt[d.w], 1);
    } else {
        for (int k = i; k < e; ++k) atomicAdd(&cnt[dst[k]], 1);
    }
}

// exclusive scan of cnt -> rowptr, plus dinv = rsqrt(cnt+1) fused.
__global__ __launch_bounds__(1024) void scan_k(const int* __restrict__ cnt,
                                               int* __restrict__ rowptr,
                                               float* __restrict__ dinv, int n) {
    __shared__ int sdata[1024];
    int tid = threadIdx.x;
    int chunk = (n + 1023) >> 10;
    int s0 = tid * chunk;
    int s1 = s0 + chunk; if (s1 > n) s1 = n;
    int sum = 0;
    for (int i = s0; i < s1; ++i) {
        int c = cnt[i];
        dinv[i] = 1.0f / sqrtf((float)(c + 1));
        sum += c;
    }
    sdata[tid] = sum;
    __syncthreads();
    for (int off = 1; off < 1024; off <<= 1) {
        int v = sdata[tid];
        int u = (tid >= off) ? sdata[tid - off] : 0;
        __syncthreads();
        sdata[tid] = v + u;
        __syncthreads();
    }
    int run = sdata[tid] - sum;   // exclusive prefix
    for (int i = s0; i < s1; ++i) { rowptr[i] = run; run += cnt[i]; }
    if (tid == 0) rowptr[n] = sdata[1023];
}

__global__ void scatter_k(const int* __restrict__ src, const int* __restrict__ dst,
                          const int* __restrict__ rowptr, int* __restrict__ cursor,
                          int* __restrict__ col, int e) {
    int i = (blockIdx.x * 256 + threadIdx.x) * 4;
    if (i + 3 < e) {
        int4 d = *(const int4*)(dst + i);
        int4 s = *(const int4*)(src + i);
        col[rowptr[d.x] + atomicAdd(&cursor[d.x], 1)] = s.x;
        col[rowptr[d.y] + atomicAdd(&cursor[d.y], 1)] = s.y;
        col[rowptr[d.z] + atomicAdd(&cursor[d.z], 1)] = s.z;
        col[rowptr[d.w] + atomicAdd(&cursor[d.w], 1)] = s.w;
    } else {
        for (int k = i; k < e; ++k) {
            int d = dst[k];
            col[rowptr[d] + atomicAdd(&cursor[d], 1)] = src[k];
        }
    }
}

// ---- big GEMM: t1s = (x @ W1) * dinv[row] -------------------------------
// 256 threads / 4 waves, 64 rows per block, K-chunk 256.
// Staging: wave w stages rows [16w,16w+16); per row ONE wave-instruction
// reads float4 #lane of the row's 1KB chunk -> fully contiguous HBM bursts.
// LDS: 4096 float4 (64KB) swizzled A4 = k4*64 + (row^k4); ds_write_b128
// spreads 8 bank-quads x 8 lanes (throughput-optimal), ds_read_b128
// conflict-free. Single LDS buffer + register double-buffer (st[16]).
// Compute: thread=(row=tid>>2, jq=tid&3): 16 FMA per k4; W1 read from
// global (16KB/chunk, L1-resident, 16-lane broadcast). No reduction.
__global__ __launch_bounds__(256, 2) void gemm1(const float* __restrict__ x,
                                                const float* __restrict__ W1,
                                                const float* __restrict__ dinv,
                                                float* __restrict__ t1s, int n) {
    __shared__ float4 xT4[RPB * KC / 4];   // 4096 f4 = 65536 B
    const int tid = threadIdx.x;
    const int w   = tid >> 6;      // wave 0..3 (staging role)
    const int l   = tid & 63;      // lane     (staging role)
    const int rb  = tid >> 2;      // row-in-block 0..63 (compute role)
    const int jq  = tid & 3;       // j-quad 0..3        (compute role)
    const long base = (long)blockIdx.x * RPB;

    float4 st[16];

#define G_LOAD(c, kc4)                                                      \
    {                                                                       \
        const long k0 = (long)(c) * KC;                                     \
        _Pragma("unroll")                                                   \
        for (int i = 0; i < 16; ++i) {                                      \
            long gr = base + w * 16 + i;                                    \
            if (gr >= n) gr = n - 1;                                        \
            if (l < (kc4)) st[i] = *(const float4*)(x + gr * FIN + k0 + 4 * l); \
        }                                                                   \
    }
#define G_WRITE(kc4)                                                        \
    if (l < (kc4)) {                                                        \
        _Pragma("unroll")                                                   \
        for (int i = 0; i < 16; ++i) {                                      \
            int r = w * 16 + i;                                             \
            xT4[l * RPB + (r ^ l)] = st[i];                                 \
        }                                                                   \
    }

    float4 acc = make_float4(0.f, 0.f, 0.f, 0.f);

    G_LOAD(0, 64);
    for (int c = 0; c < NCH; ++c) {
        const int kc4 = (c == NCH - 1) ? 52 : 64;   // tail: 208 k = 52 f4
        __syncthreads();                 // all waves done computing chunk c-1
        G_WRITE(kc4);                    // vmcnt wait on st handled by compiler
        __syncthreads();                 // LDS visible
        if (c + 1 < NCH) {
            const int nk4 = (c + 1 == NCH - 1) ? 52 : 64;
            G_LOAD(c + 1, nk4);          // next chunk flies during compute
        }
        const float* wbase = W1 + (long)c * KC * HDIM + jq * 4;
#pragma unroll 4
        for (int k4 = 0; k4 < kc4; ++k4) {
            float4 xv = xT4[k4 * RPB + (rb ^ k4)];
            const float* wp = wbase + k4 * 4 * HDIM;
            float4 w0 = *(const float4*)(wp);
            float4 w1 = *(const float4*)(wp + HDIM);
            float4 w2 = *(const float4*)(wp + 2 * HDIM);
            float4 w3 = *(const float4*)(wp + 3 * HDIM);
            acc.x = fmaf(xv.x, w0.x, acc.x); acc.y = fmaf(xv.x, w0.y, acc.y);
            acc.z = fmaf(xv.x, w0.z, acc.z); acc.w = fmaf(xv.x, w0.w, acc.w);
            acc.x = fmaf(xv.y, w1.x, acc.x); acc.y = fmaf(xv.y, w1.y, acc.y);
            acc.z = fmaf(xv.y, w1.z, acc.z); acc.w = fmaf(xv.y, w1.w, acc.w);
            acc.x = fmaf(xv.z, w2.x, acc.x); acc.y = fmaf(xv.z, w2.y, acc.y);
            acc.z = fmaf(xv.z, w2.z, acc.z); acc.w = fmaf(xv.z, w2.w, acc.w);
            acc.x = fmaf(xv.w, w3.x, acc.x); acc.y = fmaf(xv.w, w3.y, acc.y);
            acc.z = fmaf(xv.w, w3.z, acc.z); acc.w = fmaf(xv.w, w3.w, acc.w);
        }
    }
#undef G_LOAD
#undef G_WRITE

    long row = base + rb;
    if (row < n) {
        float sc = dinv[row];
        *(float4*)(t1s + row * HDIM + jq * 4) =
            make_float4(acc.x * sc, acc.y * sc, acc.z * sc, acc.w * sc);
    }
}

// ---- aggregation 1 + relu + (h @ W2) fused ------------------------------
// 16 lanes per node (one per hidden dim).
__global__ __launch_bounds__(256) void agg1(const float* __restrict__ t1s,
                                            const int* __restrict__ rowptr,
                                            const int* __restrict__ col,
                                            const float* __restrict__ dinv,
                                            const float* __restrict__ b1,
                                            const float* __restrict__ W2,
                                            float* __restrict__ t2s, int n) {
    int tid = blockIdx.x * 256 + threadIdx.x;
    int node = tid >> 4;
    int j = tid & 15;
    if (node >= n) return;
    float acc = t1s[node * HDIM + j];             // self-loop (dinv[src] pre-folded)
    int e0 = rowptr[node], e1 = rowptr[node + 1];
    for (int e = e0; e < e1; ++e) {
        int s = col[e];
        acc += t1s[s * HDIM + j];
    }
    float dn = dinv[node];
    float h = acc * dn + b1[j];
    h = h > 0.0f ? h : 0.0f;
    float p0 = h * W2[j * 3 + 0];
    float p1 = h * W2[j * 3 + 1];
    float p2 = h * W2[j * 3 + 2];
#pragma unroll
    for (int off = 8; off > 0; off >>= 1) {
        p0 += __shfl_xor(p0, off, 16);
        p1 += __shfl_xor(p1, off, 16);
        p2 += __shfl_xor(p2, off, 16);
    }
    if (j == 0) {
        *(float4*)(t2s + node * 4) = make_float4(p0 * dn, p1 * dn, p2 * dn, 0.0f);
    }
}

// ---- aggregation 2 + bias + log_softmax ---------------------------------
__global__ __launch_bounds__(256) void agg2(const float* __restrict__ t2s,
                                            const int* __restrict__ rowptr,
                                            const int* __restrict__ col,
                                            const float* __restrict__ dinv,
                                            const float* __restrict__ b2,
                                            float* __restrict__ out, int n) {
    int node = blockIdx.x * 256 + threadIdx.x;
    if (node >= n) return;
    float4 a = *(const float4*)(t2s + node * 4);
    float a0 = a.x, a1 = a.y, a2 = a.z;
    int e0 = rowptr[node], e1 = rowptr[node + 1];
#pragma unroll 4
    for (int e = e0; e < e1; ++e) {
        int s = col[e];
        float4 v = *(const float4*)(t2s + s * 4);
        a0 += v.x; a1 += v.y; a2 += v.z;
    }
    float dn = dinv[node];
    float l0 = a0 * dn + b2[0];
    float l1 = a1 * dn + b2[1];
    float l2 = a2 * dn + b2[2];
    float m = fmaxf(l0, fmaxf(l1, l2));
    float lse = logf(expf(l0 - m) + expf(l1 - m) + expf(l2 - m)) + m;
    out[node * 3 + 0] = l0 - lse;
    out[node * 3 + 1] = l1 - lse;
    out[node * 3 + 2] = l2 - lse;
}

extern "C" void kernel_launch(void* const* d_in, const int* in_sizes, int n_in,
                              void* d_out, int out_size, void* d_ws, size_t ws_size,
                              hipStream_t stream) {
    const float* x  = (const float*)d_in[0];
    const int*   ei = (const int*)d_in[1];
    const float* W1 = (const float*)d_in[2];
    const float* b1 = (const float*)d_in[3];
    const float* W2 = (const float*)d_in[4];
    const float* b2 = (const float*)d_in[5];
    const int N = in_sizes[0] / FIN;
    const int E = in_sizes[1] / 2;
    const int* src = ei;
    const int* dst = ei + E;

    char* ws = (char*)d_ws;
    auto alloc = [&](size_t bytes) {
        char* p = ws;
        ws += (bytes + 255) & ~(size_t)255;
        return p;
    };
    size_t npad = ((size_t)N * 4 + 255) & ~(size_t)255;
    int*   cnt    = (int*)alloc(N * 4);
    int*   cursor = (int*)alloc(N * 4);     // adjacent to cnt: one zero_k covers both
    int*   rowptr = (int*)alloc((size_t)(N + 1) * 4);
    float* dinv   = (float*)alloc(N * 4);
    int*   col    = (int*)alloc((size_t)E * 4);
    float* t1s    = (float*)alloc((size_t)N * HDIM * 4);
    float* t2s    = (float*)alloc((size_t)N * 4 * 4);

    int n4 = (int)(npad * 2 / 16);          // cnt+cursor region as int4s
    zero_k<<<(n4 + 255) / 256, 256, 0, stream>>>((int4*)cnt, n4);
    int e4 = (E + 3) / 4;
    count_k<<<(e4 + 255) / 256, 256, 0, stream>>>(dst, cnt, E);
    scan_k<<<1, 1024, 0, stream>>>(cnt, rowptr, dinv, N);
    scatter_k<<<(e4 + 255) / 256, 256, 0, stream>>>(src, dst, rowptr, cursor, col, E);
    gemm1<<<(N + RPB - 1) / RPB, 256, 0, stream>>>(x, W1, dinv, t1s, N);
    agg1<<<(N * 16 + 255) / 256, 256, 0, stream>>>(t1s, rowptr, col, dinv, b1, W2, t2s, N);
    agg2<<<(N + 255) / 256, 256, 0, stream>>>(t2s, rowptr, col, dinv, b2, (float*)d_out, N);
}

// Round 10
// 1112.457 us; speedup vs baseline: 1.1789x; 1.1789x over previous
//
#include <hip/hip_runtime.h>
#include <hip/hip_bf16.h>

// GCN forward: 2-layer GCNConv + log_softmax.
// N=100000, E=3200000, F_IN=2000, H=16, C=3.
//
// R9 post-mortem: gemm solo 759us, VALU 8.7%, HBM 25%, WRITE_SIZE 788MB
// (scratch spill) — inner loop stalled on per-k4 W1 VECTOR loads from
// global (L1 latency, 8 waves/CU) + st[] spill. R10 gemm:
//   - W1 chunk staged in LDS (16KB): inner loop has ZERO global loads;
//     W reads are wave-uniform -> LDS broadcast (free).
//   - thread=row (lane r = row), all 16 j in acc[16]: 64 FMA per k4 per
//     thread -> VALU-dominated inner loop (128cy FMA vs ~40cy LDS/wave).
//   - 4 waves split-K per chunk (wave w takes k4-quarter); one cross-wave
//     LDS reduce at the end.
//   - staging identical to R9 (1KB/row bursts, swizzled f4 LDS, 0 conflicts).
//   - LDS 64+16 = 80KB exactly -> 2 blocks/CU.
// Roofline: VALU floor 41us << HBM floor 127us -> target gemm ~150-185us.
//
//  K0  zero_k    : cnt+cursor = 0
//  K1  count_k   : cnt[dst]++ over edges (int4 x4 edges/thread)
//  K2  scan_k    : rowptr = exclusive_scan(cnt); dinv = rsqrt(cnt+1) fused
//  K3  scatter_k : CSR col array (int4 x4 edges/thread)
//  K4  gemm1     : t1s[row] = (x[row] @ W1) * dinv[row]
//  K5  agg1      : h = relu(dinv*(t1s[i]+sum t1s[col])+b1); t2s=(h@W2)*dinv
//  K6  agg2     : logits + log_softmax -> out

#define FIN   2000
#define HDIM  16
#define RPB   64          // rows per block
#define KC    256         // k per chunk (1KB contiguous per row read)
#define NCH   8           // 7 full chunks + tail of 208 k (52 f4)

__global__ void zero_k(int4* __restrict__ p, int n4) {
    int i = blockIdx.x * 256 + threadIdx.x;
    if (i < n4) p[i] = make_int4(0, 0, 0, 0);
}

__global__ void count_k(const int* __restrict__ dst, int* __restrict__ cnt, int e) {
    int i = (blockIdx.x * 256 + threadIdx.x) * 4;
    if (i + 3 < e) {
        int4 d = *(const int4*)(dst + i);
        atomicAdd(&cnt[d.x], 1);
        atomicAdd(&cnt[d.y], 1);
        atomicAdd(&cnt[d.z], 1);
        atomicAdd(&cnt[d.w], 1);
    } else {
        for (int k = i; k < e; ++k) atomicAdd(&cnt[dst[k]], 1);
    }
}

// exclusive scan of cnt -> rowptr, plus dinv = rsqrt(cnt+1) fused.
__global__ __launch_bounds__(1024) void scan_k(const int* __restrict__ cnt,
                                               int* __restrict__ rowptr,
                                               float* __restrict__ dinv, int n) {
    __shared__ int sdata[1024];
    int tid = threadIdx.x;
    int chunk = (n + 1023) >> 10;
    int s0 = tid * chunk;
    int s1 = s0 + chunk; if (s1 > n) s1 = n;
    int sum = 0;
    for (int i = s0; i < s1; ++i) {
        int c = cnt[i];
        dinv[i] = 1.0f / sqrtf((float)(c + 1));
        sum += c;
    }
    sdata[tid] = sum;
    __syncthreads();
    for (int off = 1; off < 1024; off <<= 1) {
        int v = sdata[tid];
        int u = (tid >= off) ? sdata[tid - off] : 0;
        __syncthreads();
        sdata[tid] = v + u;
        __syncthreads();
    }
    int run = sdata[tid] - sum;   // exclusive prefix
    for (int i = s0; i < s1; ++i) { rowptr[i] = run; run += cnt[i]; }
    if (tid == 0) rowptr[n] = sdata[1023];
}

__global__ void scatter_k(const int* __restrict__ src, const int* __restrict__ dst,
                          const int* __restrict__ rowptr, int* __restrict__ cursor,
                          int* __restrict__ col, int e) {
    int i = (blockIdx.x * 256 + threadIdx.x) * 4;
    if (i + 3 < e) {
        int4 d = *(const int4*)(dst + i);
        int4 s = *(const int4*)(src + i);
        col[rowptr[d.x] + atomicAdd(&cursor[d.x], 1)] = s.x;
        col[rowptr[d.y] + atomicAdd(&cursor[d.y], 1)] = s.y;
        col[rowptr[d.z] + atomicAdd(&cursor[d.z], 1)] = s.z;
        col[rowptr[d.w] + atomicAdd(&cursor[d.w], 1)] = s.w;
    } else {
        for (int k = i; k < e; ++k) {
            int d = dst[k];
            col[rowptr[d] + atomicAdd(&cursor[d], 1)] = src[k];
        }
    }
}

// ---- big GEMM: t1s = (x @ W1) * dinv[row] -------------------------------
// 256 threads / 4 waves, 64 rows, K-chunk 256.
// Staging (R9-proven): wave w stages rows [16w,16w+16); per row one
// wave-instruction reads the row's 1KB chunk (lane = f4 index) -> contiguous
// bursts; LDS x stored swizzled xT4[k4*64 + (row^k4)] (0 conflicts).
// W1 chunk (256x16 = 16KB) staged linearly; inner-loop W reads are
// wave-uniform -> broadcast.
// Compute: lane r = row; wave w covers k4 in [span*w, span*(w+1)); 64 FMA
// per k4 into acc[16]. Epilogue: waves 1-3 dump acc to LDS (x buffer
// reused), wave 0 sums, scales by dinv, writes 64B/row.
__global__ __launch_bounds__(256, 2) void gemm1(const float* __restrict__ x,
                                                const float* __restrict__ W1,
                                                const float* __restrict__ dinv,
                                                float* __restrict__ t1s, int n) {
    __shared__ float4 xT4[RPB * KC / 4];    // 4096 f4 = 64 KB
    __shared__ float4 wT4[KC * HDIM / 4];   // 1024 f4 = 16 KB (total 80 KB)
    const int tid = threadIdx.x;
    const int w   = tid >> 6;      // wave id
    const int l   = tid & 63;      // lane (= row in compute role)
    const long base = (long)blockIdx.x * RPB;

    float4 st[16];                 // x staging registers
    float4 wst[4];                 // W staging registers

#define G_LOAD(c, kc4)                                                      \
    {                                                                       \
        const long k0 = (long)(c) * KC;                                     \
        _Pragma("unroll")                                                   \
        for (int i = 0; i < 16; ++i) {                                      \
            long gr = base + w * 16 + i;                                    \
            if (gr >= n) gr = n - 1;                                        \
            if (l < (kc4)) st[i] = *(const float4*)(x + gr * FIN + k0 + 4 * l); \
        }                                                                   \
    }
#define G_WRITE(kc4)                                                        \
    if (l < (kc4)) {                                                        \
        _Pragma("unroll")                                                   \
        for (int i = 0; i < 16; ++i) {                                      \
            int r = w * 16 + i;                                             \
            xT4[l * RPB + (r ^ l)] = st[i];                                 \
        }                                                                   \
    }
#define W_LOAD(c, nw4)                                                      \
    {                                                                       \
        const float4* wsrc = (const float4*)(W1 + (long)(c) * KC * HDIM);   \
        _Pragma("unroll")                                                   \
        for (int i = 0; i < 4; ++i)                                         \
            if (tid + 256 * i < (nw4)) wst[i] = wsrc[tid + 256 * i];        \
    }
#define W_WRITE(nw4)                                                        \
    {                                                                       \
        _Pragma("unroll")                                                   \
        for (int i = 0; i < 4; ++i)                                         \
            if (tid + 256 * i < (nw4)) wT4[tid + 256 * i] = wst[i];         \
    }

    float acc[HDIM];
#pragma unroll
    for (int j = 0; j < HDIM; ++j) acc[j] = 0.0f;

    G_LOAD(0, 64);
    W_LOAD(0, 1024);
    for (int c = 0; c < NCH; ++c) {
        const int kc4 = (c == NCH - 1) ? 52 : 64;       // f4 per row this chunk
        const int nw4 = (c == NCH - 1) ? 832 : 1024;    // W f4 this chunk
        __syncthreads();               // previous chunk's compute done
        G_WRITE(kc4);
        W_WRITE(nw4);
        __syncthreads();               // staged data visible
        if (c + 1 < NCH) {
            const int nk4 = (c + 1 == NCH - 1) ? 52 : 64;
            const int nn4 = (c + 1 == NCH - 1) ? 832 : 1024;
            G_LOAD(c + 1, nk4);        // next chunk in flight during compute
            W_LOAD(c + 1, nn4);
        }
        // compute: wave w covers k4 in [span*w, span*(w+1))
        const int span = kc4 >> 2;     // 16 or 13
        for (int i = 0; i < span; ++i) {
            int K = span * w + i;
            float4 xv = xT4[K * RPB + (l ^ K)];
            const float4* wr = wT4 + (K * 4) * (HDIM / 4);  // W rows 4K..4K+3
#pragma unroll
            for (int kk = 0; kk < 4; ++kk) {
                float xs = kk == 0 ? xv.x : kk == 1 ? xv.y : kk == 2 ? xv.z : xv.w;
#pragma unroll
                for (int j4 = 0; j4 < 4; ++j4) {
                    float4 wv = wr[kk * 4 + j4];
                    acc[j4 * 4 + 0] = fmaf(xs, wv.x, acc[j4 * 4 + 0]);
                    acc[j4 * 4 + 1] = fmaf(xs, wv.y, acc[j4 * 4 + 1]);
                    acc[j4 * 4 + 2] = fmaf(xs, wv.z, acc[j4 * 4 + 2]);
                    acc[j4 * 4 + 3] = fmaf(xs, wv.w, acc[j4 * 4 + 3]);
                }
            }
        }
    }
#undef G_LOAD
#undef G_WRITE
#undef W_LOAD
#undef W_WRITE

    // ---- cross-wave K-split reduction (reuse xT4 as scratch) ----
    __syncthreads();
    float4* red = xT4;
    if (w > 0) {
#pragma unroll
        for (int j4 = 0; j4 < 4; ++j4)
            red[((w - 1) * 64 + l) * 4 + j4] =
                make_float4(acc[j4 * 4 + 0], acc[j4 * 4 + 1],
                            acc[j4 * 4 + 2], acc[j4 * 4 + 3]);
    }
    __syncthreads();
    if (w == 0) {
#pragma unroll
        for (int ww = 0; ww < 3; ++ww) {
#pragma unroll
            for (int j4 = 0; j4 < 4; ++j4) {
                float4 v = red[(ww * 64 + l) * 4 + j4];
                acc[j4 * 4 + 0] += v.x;
                acc[j4 * 4 + 1] += v.y;
                acc[j4 * 4 + 2] += v.z;
                acc[j4 * 4 + 3] += v.w;
            }
        }
        long row = base + l;
        if (row < n) {
            float sc = dinv[row];
            float4* o = (float4*)(t1s + row * HDIM);
            o[0] = make_float4(acc[0] * sc, acc[1] * sc, acc[2] * sc, acc[3] * sc);
            o[1] = make_float4(acc[4] * sc, acc[5] * sc, acc[6] * sc, acc[7] * sc);
            o[2] = make_float4(acc[8] * sc, acc[9] * sc, acc[10] * sc, acc[11] * sc);
            o[3] = make_float4(acc[12] * sc, acc[13] * sc, acc[14] * sc, acc[15] * sc);
        }
    }
}

// ---- aggregation 1 + relu + (h @ W2) fused ------------------------------
// 16 lanes per node (one per hidden dim).
__global__ __launch_bounds__(256) void agg1(const float* __restrict__ t1s,
                                            const int* __restrict__ rowptr,
                                            const int* __restrict__ col,
                                            const float* __restrict__ dinv,
                                            const float* __restrict__ b1,
                                            const float* __restrict__ W2,
                                            float* __restrict__ t2s, int n) {
    int tid = blockIdx.x * 256 + threadIdx.x;
    int node = tid >> 4;
    int j = tid & 15;
    if (node >= n) return;
    float acc = t1s[node * HDIM + j];             // self-loop (dinv[src] pre-folded)
    int e0 = rowptr[node], e1 = rowptr[node + 1];
    for (int e = e0; e < e1; ++e) {
        int s = col[e];
        acc += t1s[s * HDIM + j];
    }
    float dn = dinv[node];
    float h = acc * dn + b1[j];
    h = h > 0.0f ? h : 0.0f;
    float p0 = h * W2[j * 3 + 0];
    float p1 = h * W2[j * 3 + 1];
    float p2 = h * W2[j * 3 + 2];
#pragma unroll
    for (int off = 8; off > 0; off >>= 1) {
        p0 += __shfl_xor(p0, off, 16);
        p1 += __shfl_xor(p1, off, 16);
        p2 += __shfl_xor(p2, off, 16);
    }
    if (j == 0) {
        *(float4*)(t2s + node * 4) = make_float4(p0 * dn, p1 * dn, p2 * dn, 0.0f);
    }
}

// ---- aggregation 2 + bias + log_softmax ---------------------------------
__global__ __launch_bounds__(256) void agg2(const float* __restrict__ t2s,
                                            const int* __restrict__ rowptr,
                                            const int* __restrict__ col,
                                            const float* __restrict__ dinv,
                                            const float* __restrict__ b2,
                                            float* __restrict__ out, int n) {
    int node = blockIdx.x * 256 + threadIdx.x;
    if (node >= n) return;
    float4 a = *(const float4*)(t2s + node * 4);
    float a0 = a.x, a1 = a.y, a2 = a.z;
    int e0 = rowptr[node], e1 = rowptr[node + 1];
#pragma unroll 4
    for (int e = e0; e < e1; ++e) {
        int s = col[e];
        float4 v = *(const float4*)(t2s + s * 4);
        a0 += v.x; a1 += v.y; a2 += v.z;
    }
    float dn = dinv[node];
    float l0 = a0 * dn + b2[0];
    float l1 = a1 * dn + b2[1];
    float l2 = a2 * dn + b2[2];
    float m = fmaxf(l0, fmaxf(l1, l2));
    float lse = logf(expf(l0 - m) + expf(l1 - m) + expf(l2 - m)) + m;
    out[node * 3 + 0] = l0 - lse;
    out[node * 3 + 1] = l1 - lse;
    out[node * 3 + 2] = l2 - lse;
}

extern "C" void kernel_launch(void* const* d_in, const int* in_sizes, int n_in,
                              void* d_out, int out_size, void* d_ws, size_t ws_size,
                              hipStream_t stream) {
    const float* x  = (const float*)d_in[0];
    const int*   ei = (const int*)d_in[1];
    const float* W1 = (const float*)d_in[2];
    const float* b1 = (const float*)d_in[3];
    const float* W2 = (const float*)d_in[4];
    const float* b2 = (const float*)d_in[5];
    const int N = in_sizes[0] / FIN;
    const int E = in_sizes[1] / 2;
    const int* src = ei;
    const int* dst = ei + E;

    char* ws = (char*)d_ws;
    auto alloc = [&](size_t bytes) {
        char* p = ws;
        ws += (bytes + 255) & ~(size_t)255;
        return p;
    };
    size_t npad = ((size_t)N * 4 + 255) & ~(size_t)255;
    int*   cnt    = (int*)alloc(N * 4);
    int*   cursor = (int*)alloc(N * 4);     // adjacent to cnt: one zero_k covers both
    int*   rowptr = (int*)alloc((size_t)(N + 1) * 4);
    float* dinv   = (float*)alloc(N * 4);
    int*   col    = (int*)alloc((size_t)E * 4);
    float* t1s    = (float*)alloc((size_t)N * HDIM * 4);
    float* t2s    = (float*)alloc((size_t)N * 4 * 4);

    int n4 = (int)(npad * 2 / 16);          // cnt+cursor region as int4s
    zero_k<<<(n4 + 255) / 256, 256, 0, stream>>>((int4*)cnt, n4);
    int e4 = (E + 3) / 4;
    count_k<<<(e4 + 255) / 256, 256, 0, stream>>>(dst, cnt, E);
    scan_k<<<1, 1024, 0, stream>>>(cnt, rowptr, dinv, N);
    scatter_k<<<(e4 + 255) / 256, 256, 0, stream>>>(src, dst, rowptr, cursor, col, E);
    gemm1<<<(N + RPB - 1) / RPB, 256, 0, stream>>>(x, W1, dinv, t1s, N);
    agg1<<<(N * 16 + 255) / 256, 256, 0, stream>>>(t1s, rowptr, col, dinv, b1, W2, t2s, N);
    agg2<<<(N + 255) / 256, 256, 0, stream>>>(t2s, rowptr, col, dinv, b2, (float*)d_out, N);
}